// Round 10
// baseline (1851.953 us; speedup 1.0000x reference)
//
#include <hip/hip_runtime.h>
#include <math.h>

#define NT 256
#define G 4

// fp32 problem. R10: LDS diet for occupancy — bf16 xbar/mid/uL, mid+ob aliased
// into the dead-X pool, packed-uint xbar phase. k_parent LDS ~24.6KB -> 6 blk/CU.

enum {
  I_LEAF = 0, I_SUB, I_SAW, I_SAB, I_LAW, I_LAB, I_PAW, I_PAB,
  I_SCLS, I_SWQKV, I_SBQKV, I_SWO, I_SBO, I_SLNG, I_SLNB, I_SW1, I_SB1, I_SW2, I_SB2,
  I_PCLS, I_PWQKV, I_PBQKV, I_PWO, I_PBO, I_PLNG, I_PLNB, I_PW1, I_PB1, I_PW2, I_PB2,
  I_CLFW, I_CLFB
};

struct P {
  const float* in[32];
  float* parent_al;  // ws [B][2][128]
  float* vecs;       // ws [B][3][128]
  float* out;        // [B][2]
};

using u16 = unsigned short;

__device__ __forceinline__ float uplo(unsigned int u) { return __uint_as_float(u << 16); }
__device__ __forceinline__ float uphi(unsigned int u) { return __uint_as_float(u & 0xffff0000u); }
__device__ __forceinline__ float B16F(u16 v) { return __uint_as_float((unsigned int)v << 16); }
__device__ __forceinline__ u16 F2B(float f) {  // RNE
  unsigned int u = __float_as_uint(f);
  return (u16)((u + 0x7FFFu + ((u >> 16) & 1u)) >> 16);
}
__device__ __forceinline__ void LD8(const float* p, float* o) {
  float4 a = ((const float4*)p)[0], b = ((const float4*)p)[1];
  o[0] = a.x; o[1] = a.y; o[2] = a.z; o[3] = a.w;
  o[4] = b.x; o[5] = b.y; o[6] = b.z; o[7] = b.w;
}
__device__ __forceinline__ void LDB8(const u16* p, float* o) {  // 8 bf16 -> fp32 (16B)
  uint4 u = *(const uint4*)p;
  o[0] = uplo(u.x); o[1] = uphi(u.x); o[2] = uplo(u.y); o[3] = uphi(u.y);
  o[4] = uplo(u.z); o[5] = uphi(u.z); o[6] = uplo(u.w); o[7] = uphi(u.w);
}
__device__ __forceinline__ void fma8(float& acc, const float* x, const float* w) {
#pragma unroll
  for (int i = 0; i < 8; ++i) acc += x[i] * w[i];
}
__device__ __forceinline__ float red8(float v) {  // reduce within 8 consecutive lanes
  v += __shfl_xor(v, 1, 64);
  v += __shfl_xor(v, 2, 64);
  v += __shfl_xor(v, 4, 64);
  return v;
}
__device__ __forceinline__ float gelu(float v) {
  return 0.5f * v * (1.0f + erff(v * 0.70710678118654752f));
}

// LayerNorm rows in place: buf [G][E]; one wave per row (G=4).
template <int E>
__device__ void ln_rows(float* buf, const float* __restrict__ gg, const float* __restrict__ bb) {
  const int w = threadIdx.x >> 6, lane = threadIdx.x & 63;
  for (int g = w; g < G; g += 4) {
    float* row = buf + g * E;
    float s = 0.f, s2 = 0.f;
    for (int e = lane; e < E; e += 64) { float x = row[e]; s += x; s2 += x * x; }
#pragma unroll
    for (int off = 1; off < 64; off <<= 1) {
      s += __shfl_xor(s, off, 64);
      s2 += __shfl_xor(s2, off, 64);
    }
    float m = s / (float)E;
    float inv = 1.0f / sqrtf(s2 / (float)E - m * m + 1e-5f);
    for (int e = lane; e < E; e += 64) row[e] = (row[e] - m) * inv * gg[e] + bb[e];
  }
}

// q = Wq.cls + bq (coalesced k-split) ; uLb (bf16) = scale*Wk_h^T q_h ; sb_h
template <int E>
__device__ void compute_usb(const float* __restrict__ Wq, const float* __restrict__ bq,
                            const float* __restrict__ clsb, float* qb,
                            u16* uLb, float* sbL) {
  const int tid = threadIdx.x;
  constexpr int D = E / 4;
  const float scale = (D == 16) ? 0.25f : 0.17677669529663687f;
  const int ks = tid & 7, eb = tid >> 3;
  for (int e = eb; e < E; e += NT / 8) {
    const float* w = Wq + (size_t)e * E + ks * 8;
    float acc = 0.f;
    for (int kc = 0; kc < E; kc += 64) {
      float wv[8], xv[8];
      LD8(w + kc, wv);
      LD8(clsb + kc + ks * 8, xv);
      fma8(acc, xv, wv);
    }
    acc = red8(acc);
    if (ks == 0) qb[e] = bq[e] + acc;
  }
  __syncthreads();
  if (tid < E) {
    for (int h = 0; h < 4; ++h) {
      float acc = 0.f;
      for (int d = 0; d < D; ++d)
        acc += Wq[(size_t)(E + h * D + d) * E + tid] * qb[h * D + d];
      uLb[h * E + tid] = F2B(acc * scale);
    }
  }
  if (tid < 4) {
    float acc = 0.f;
    for (int d = 0; d < D; ++d) acc += qb[tid * D + d] * bq[E + tid * D + d];
    sbL[tid] = acc * scale;
  }
  __syncthreads();
}

// Folded CLS-only aggregator over G batches. X: LDS bf16, row (t*G+g), E elems.
// mid (bf16) and ob (fp32) may alias the X pool: X is dead after the xbar
// phase; ob first written in Wv (outside X's live range in the pool layout),
// mid first written in FFN1. Result fp32 [G][E] in ob. Ends with barrier.
template <int E, int T>
__device__ void agg_run(const u16* __restrict__ X, const float* __restrict__ clsb,
                        const u16* __restrict__ uLb, const float* __restrict__ sbL,
                        const float* __restrict__ Wv, const float* __restrict__ bv,
                        const float* __restrict__ Wo, const float* __restrict__ bo,
                        const float* __restrict__ lng, const float* __restrict__ lnb,
                        const float* __restrict__ W1, const float* __restrict__ b1,
                        const float* __restrict__ W2, const float* __restrict__ b2,
                        float* att, u16* xbar, float* ob, float* hb, u16* mid) {
  const int tid = threadIdx.x;
  const int wid = tid >> 6, lane = tid & 63;
  const int ks = tid & 7, eb = tid >> 3;
  constexpr int S = T + 1, D = E / 4;
  constexpr int GPT = (G * E) / NT;          // outputs/thread in FFN2
  constexpr int M1 = (4 * E) / NT;           // FFN1 outputs/thread

  // ---- scores[g][h][s] = sb[h] + x_s . u_h : one dot per wave-iteration ----
  for (int i = wid; i < G * 4 * S; i += 4) {
    int s = i % S, hh = (i / S) % 4, g = i / (4 * S);
    float part = 0.f;
    if (lane < E / 2) {
      unsigned int uv = ((const unsigned int*)(uLb + hh * E))[lane];
      if (s == 0) {
        float2 c2 = ((const float2*)clsb)[lane];
        part = c2.x * uplo(uv) + c2.y * uphi(uv);
      } else {
        unsigned int xv = ((const unsigned int*)(X + ((s - 1) * G + g) * E))[lane];
        part = uplo(xv) * uplo(uv) + uphi(xv) * uphi(uv);
      }
    }
#pragma unroll
    for (int off = 1; off < 64; off <<= 1) part += __shfl_xor(part, off, 64);
    if (lane == 0) att[(g * 4 + hh) * S + s] = sbL[hh] + part;
  }
  __syncthreads();
  // ---- softmax over s ----
  for (int i = tid; i < G * 4; i += NT) {
    float* a = att + i * S;
    float mx = a[0];
    for (int s = 1; s < S; ++s) mx = fmaxf(mx, a[s]);
    float sum = 0.f;
    for (int s = 0; s < S; ++s) { float e = expf(a[s] - mx); a[s] = e; sum += e; }
    float inv = 1.0f / sum;
    for (int s = 0; s < S; ++s) a[s] *= inv;
  }
  __syncthreads();
  // ---- xbar[g][h][k] = a0*cls[k] + sum_s att*x_s[k]  (2 k's per thread, packed) ----
  for (int i = tid; i < G * 4 * (E / 2); i += NT) {
    int k2 = i % (E / 2), hh = (i / (E / 2)) % 4, g = i / (4 * (E / 2));
    const float* a = att + (g * 4 + hh) * S;
    float acc0 = a[0] * clsb[2 * k2], acc1 = a[0] * clsb[2 * k2 + 1];
    for (int s = 1; s < S; ++s) {
      unsigned int xv = ((const unsigned int*)(X + ((s - 1) * G + g) * E))[k2];
      acc0 += a[s] * uplo(xv);
      acc1 += a[s] * uphi(xv);
    }
    ((unsigned int*)xbar)[(g * 4 + hh) * (E / 2) + k2] =
        (unsigned int)F2B(acc0) | ((unsigned int)F2B(acc1) << 16);
  }
  __syncthreads();
  // ---- ob[g][e] = bv[e] + Wv[e][:] . xbar[g][head(e)][:]  (k-split, coalesced) ----
  // (first write into the pool; X region is dead from here on)
  for (int e = eb; e < E; e += NT / 8) {
    const int hh = e / D;
    const float* w = Wv + (size_t)e * E + ks * 8;
    float acc[G];
#pragma unroll
    for (int g = 0; g < G; ++g) acc[g] = 0.f;
    for (int kc = 0; kc < E; kc += 64) {
      float wv[8];
      LD8(w + kc, wv);
#pragma unroll
      for (int g = 0; g < G; ++g) {
        float xv[8];
        LDB8(xbar + (g * 4 + hh) * E + kc + ks * 8, xv);
        fma8(acc[g], xv, wv);
      }
    }
#pragma unroll
    for (int g = 0; g < G; ++g) {
      float v = red8(acc[g]);
      if (ks == 0) ob[g * E + e] = bv[e] + v;
    }
  }
  __syncthreads();
  // ---- hb[g][e] = bo[e] + cls[e] + Wo[e][:] . ob[g][:]  (k-split, coalesced) ----
  for (int e = eb; e < E; e += NT / 8) {
    const float* w = Wo + (size_t)e * E + ks * 8;
    float acc[G];
#pragma unroll
    for (int g = 0; g < G; ++g) acc[g] = 0.f;
    for (int kc = 0; kc < E; kc += 64) {
      float wv[8];
      LD8(w + kc, wv);
#pragma unroll
      for (int g = 0; g < G; ++g) {
        float xv[8];
        LD8(ob + g * E + kc + ks * 8, xv);
        fma8(acc[g], xv, wv);
      }
    }
#pragma unroll
    for (int g = 0; g < G; ++g) {
      float v = red8(acc[g]);
      if (ks == 0) hb[g * E + e] = bo[e] + clsb[e] + v;
    }
  }
  __syncthreads();
  ln_rows<E>(hb, lng, lnb);
  __syncthreads();
  // ---- FFN1: mid[g][m] = gelu(hb[g] @ W1 + b1)  (bf16 store, packed) ----
  {
    float acc[M1][G];
#pragma unroll
    for (int r = 0; r < M1; ++r)
#pragma unroll
      for (int g = 0; g < G; ++g) acc[r][g] = 0.f;
    for (int j = 0; j < E; j += 8) {
      float wv[M1][8];
#pragma unroll
      for (int ii = 0; ii < 8; ++ii) {
        if constexpr (M1 == 2) {
          float2 w2 = *(const float2*)(W1 + (size_t)(j + ii) * 4 * E + 2 * tid);
          wv[0][ii] = w2.x;
          wv[1][ii] = w2.y;
        } else {
          wv[0][ii] = W1[(size_t)(j + ii) * 4 * E + tid];
        }
      }
#pragma unroll
      for (int g = 0; g < G; ++g) {
        float xv[8];
        LD8(hb + g * E + j, xv);
#pragma unroll
        for (int r = 0; r < M1; ++r) fma8(acc[r][g], xv, wv[r]);
      }
    }
    if constexpr (M1 == 2) {
#pragma unroll
      for (int g = 0; g < G; ++g) {
        float v0 = gelu(acc[0][g] + b1[2 * tid]);
        float v1 = gelu(acc[1][g] + b1[2 * tid + 1]);
        ((unsigned int*)mid)[g * (2 * E) + tid] =
            (unsigned int)F2B(v0) | ((unsigned int)F2B(v1) << 16);
      }
    } else {
#pragma unroll
      for (int g = 0; g < G; ++g)
        mid[g * 4 * E + tid] = F2B(gelu(acc[0][g] + b1[tid]));
    }
  }
  __syncthreads();
  // ---- FFN2 + residual -> ob; LN2 ----
  {
    const int e = tid % E, gp = tid / E;
    float acc[GPT];
#pragma unroll
    for (int r = 0; r < GPT; ++r) acc[r] = 0.f;
    for (int m = 0; m < 4 * E; m += 8) {
      float wv[8];
#pragma unroll
      for (int ii = 0; ii < 8; ++ii) wv[ii] = W2[(size_t)(m + ii) * E + e];
#pragma unroll
      for (int r = 0; r < GPT; ++r) {
        float xv[8];
        LDB8(mid + (gp * GPT + r) * 4 * E + m, xv);
        fma8(acc[r], xv, wv);
      }
    }
#pragma unroll
    for (int r = 0; r < GPT; ++r) {
      int g = gp * GPT + r;
      ob[g * E + e] = b2[e] + hb[g * E + e] + acc[r];
    }
  }
  __syncthreads();
  ln_rows<E>(ob, lng, lnb);
  __syncthreads();
}

// ===================== kernel 1: sub path =====================
__global__ __launch_bounds__(NT, 8) void k_sub(P p) {
  __shared__ __align__(16) u16 pool[8 * G * 64];   // X1; later mid(1024 u16)+ob(256 f)
  __shared__ __align__(16) u16 X2[3 * G * 64];
  __shared__ __align__(16) float clsb[64];
  __shared__ __align__(16) u16 uLb[4 * 64];
  __shared__ __align__(16) float sbL[4];
  __shared__ __align__(16) float attq[G * 4 * 9];   // also usb qb scratch (>=64 f)
  __shared__ __align__(16) u16 xbar[G * 4 * 64];
  __shared__ __align__(16) float hb[G * 64];
  __shared__ __align__(16) float vec1[G * 64];
  u16* X1 = pool;
  u16* mid = pool;                                  // [0, 1024) u16
  float* ob = (float*)(pool + 1024);                // [2048, 3072) bytes
  const int tid = threadIdx.x, b0 = blockIdx.x * G;

  // subfield align: X[f][g][e]
  const float* subf = p.in[I_SUB];
  const float* saW = p.in[I_SAW];
  const float* sab = p.in[I_SAB];
  for (int i = tid; i < 11 * 64; i += NT) {
    int f = i / 64, e = i % 64;
    float bias = sab[f * 64 + e];
    float acc[G];
#pragma unroll
    for (int g = 0; g < G; ++g) acc[g] = bias;
    for (int d = 0; d < 32; d += 8) {
      float wv[8];
#pragma unroll
      for (int ii = 0; ii < 8; ++ii) wv[ii] = saW[(size_t)(f * 32 + d + ii) * 64 + e];
#pragma unroll
      for (int g = 0; g < G; ++g) {
        float xv[8];
        LD8(subf + (size_t)(b0 + g) * 352 + f * 32 + d, xv);
        fma8(acc[g], xv, wv);
      }
    }
#pragma unroll
    for (int g = 0; g < G; ++g) {
      if (f < 8) X1[(f * G + g) * 64 + e] = F2B(acc[g]);
      else       X2[((f - 8) * G + g) * 64 + e] = F2B(acc[g]);
    }
  }
  if (tid < 64) clsb[tid] = p.in[I_SCLS][tid];
  __syncthreads();

  // agg1: tcp.flags (subfields 0..7)
  compute_usb<64>(p.in[I_SWQKV], p.in[I_SBQKV], clsb, attq, uLb, sbL);
  agg_run<64, 8>(X1, clsb, uLb, sbL,
                 p.in[I_SWQKV] + 2 * 64 * 64, p.in[I_SBQKV] + 128,
                 p.in[I_SWO], p.in[I_SBO], p.in[I_SLNG], p.in[I_SLNB],
                 p.in[I_SW1], p.in[I_SB1], p.in[I_SW2], p.in[I_SB2],
                 attq, xbar, ob, hb, mid);
  for (int i = tid; i < G * 64; i += NT) vec1[i] = ob[i];
  if (tid < 64) clsb[tid] = p.in[I_SCLS][64 + tid];
  __syncthreads();

  // agg2: ip.flags (subfields 8..10)
  compute_usb<64>(p.in[I_SWQKV] + 192 * 64, p.in[I_SBQKV] + 192, clsb, attq, uLb, sbL);
  agg_run<64, 3>(X2, clsb, uLb, sbL,
                 p.in[I_SWQKV] + 192 * 64 + 2 * 64 * 64, p.in[I_SBQKV] + 192 + 128,
                 p.in[I_SWO] + 64 * 64, p.in[I_SBO] + 64,
                 p.in[I_SLNG] + 64, p.in[I_SLNB] + 64,
                 p.in[I_SW1] + 64 * 256, p.in[I_SB1] + 256,
                 p.in[I_SW2] + 256 * 64, p.in[I_SB2] + 64,
                 attq, xbar, ob, hb, mid);

  // parent_al: [:,0] = tcpf @ paW0 + pab0 ; [:,1] = ipf @ paW1 + pab1
  {
    const int pi = tid >> 7, e = tid & 127;
    const float* paW = p.in[I_PAW];
    float bias = p.in[I_PAB][pi * 128 + e];
    float acc[G];
#pragma unroll
    for (int g = 0; g < G; ++g) acc[g] = bias;
    const float* src = pi ? ob : vec1;
    for (int j = 0; j < 64; j += 8) {
      float wv[8];
#pragma unroll
      for (int ii = 0; ii < 8; ++ii) wv[ii] = paW[(size_t)(pi * 64 + j + ii) * 128 + e];
#pragma unroll
      for (int g = 0; g < G; ++g) {
        float xv[8];
        LD8(src + g * 64 + j, xv);
        fma8(acc[g], xv, wv);
      }
    }
#pragma unroll
    for (int g = 0; g < G; ++g)
      p.parent_al[(size_t)(b0 + g) * 256 + pi * 128 + e] = acc[g];
  }
}

// ===================== kernel 2: parent aggs =====================
template <int T, int F, int F0, int PAR, int AI>
__device__ void parent_body(const P& p, int b0, u16* pool, float* clsb,
                            u16* uLb, float* sbL, float* attq, u16* xbar,
                            float* hb) {
  const int tid = threadIdx.x;
  u16* X = pool;
  u16* mid = pool;                                  // [0, 2048) u16
  float* ob = (float*)(pool + 2048);                // [4096, 6144) bytes
  const float* leaf = p.in[I_LEAF];
  const float* laW = p.in[I_LAW];
  const float* lab = p.in[I_LAB];
  for (int i = tid; i < F * 128; i += NT) {
    int f = i / 128, e = i % 128;
    float bias = lab[(F0 + f) * 128 + e];
    float acc[G];
#pragma unroll
    for (int g = 0; g < G; ++g) acc[g] = bias;
    for (int d = 0; d < 32; d += 8) {
      float wv[8];
#pragma unroll
      for (int ii = 0; ii < 8; ++ii)
        wv[ii] = laW[(size_t)((F0 + f) * 32 + d + ii) * 128 + e];
#pragma unroll
      for (int g = 0; g < G; ++g) {
        float xv[8];
        LD8(leaf + (size_t)(b0 + g) * 1088 + (F0 + f) * 32 + d, xv);
        fma8(acc[g], xv, wv);
      }
    }
#pragma unroll
    for (int g = 0; g < G; ++g) X[(f * G + g) * 128 + e] = F2B(acc[g]);
  }
  if (PAR >= 0) {
    for (int i = tid; i < G * 128; i += NT) {
      int g = i / 128, e = i % 128;
      X[((T - 1) * G + g) * 128 + e] =
          F2B(p.parent_al[(size_t)(b0 + g) * 256 + PAR * 128 + e]);
    }
  }
  if (tid < 128) clsb[tid] = p.in[I_PCLS][AI * 128 + tid];
  __syncthreads();
  compute_usb<128>(p.in[I_PWQKV] + (size_t)AI * 384 * 128, p.in[I_PBQKV] + AI * 384,
                   clsb, attq, uLb, sbL);
  agg_run<128, T>(X, clsb, uLb, sbL,
                  p.in[I_PWQKV] + (size_t)AI * 384 * 128 + 2 * 128 * 128,
                  p.in[I_PBQKV] + AI * 384 + 256,
                  p.in[I_PWO] + (size_t)AI * 128 * 128, p.in[I_PBO] + AI * 128,
                  p.in[I_PLNG] + AI * 128, p.in[I_PLNB] + AI * 128,
                  p.in[I_PW1] + (size_t)AI * 128 * 512, p.in[I_PB1] + AI * 512,
                  p.in[I_PW2] + (size_t)AI * 512 * 128, p.in[I_PB2] + AI * 128,
                  attq, xbar, ob, hb, mid);
  for (int i = tid; i < G * 128; i += NT) {
    int e = i % 128, g = i / 128;
    p.vecs[(size_t)(b0 + g) * 384 + AI * 128 + e] = ob[g * 128 + e];
  }
}

__global__ __launch_bounds__(NT, 6) void k_parent(P p) {
  __shared__ __align__(16) u16 pool[16 * G * 128];  // X; later mid+ob
  __shared__ __align__(16) float clsb[128];
  __shared__ __align__(16) u16 uLb[4 * 128];
  __shared__ __align__(16) float sbL[4];
  __shared__ __align__(16) float attq[G * 4 * 17];  // also usb qb scratch (>=128 f)
  __shared__ __align__(16) u16 xbar[G * 4 * 128];
  __shared__ __align__(16) float hb[G * 128];
  const int b0 = blockIdx.x * G;
  if (blockIdx.y == 0)
    parent_body<8, 8, 0, -1, 0>(p, b0, pool, clsb, uLb, sbL, attq, xbar, hb);
  else if (blockIdx.y == 1)
    parent_body<12, 11, 8, 1, 1>(p, b0, pool, clsb, uLb, sbL, attq, xbar, hb);
  else
    parent_body<16, 15, 19, 0, 2>(p, b0, pool, clsb, uLb, sbL, attq, xbar, hb);
}

// ===================== kernel 3: pkt agg + classifier =====================
__global__ __launch_bounds__(NT, 8) void k_pkt(P p) {
  __shared__ __align__(16) u16 pool[3072];          // X (1536 u16); mid(2048)+ob
  __shared__ __align__(16) float clsb[128];
  __shared__ __align__(16) u16 uLb[4 * 128];
  __shared__ __align__(16) float sbL[4];
  __shared__ __align__(16) float attq[128];         // max(G*4*S=64, qb E=128)
  __shared__ __align__(16) u16 xbar[G * 4 * 128];
  __shared__ __align__(16) float hb[G * 128];
  u16* X = pool;
  u16* mid = pool;                                  // [0, 2048) u16
  float* ob = (float*)(pool + 2048);                // [4096, 6144) bytes
  const int tid = threadIdx.x, b0 = blockIdx.x * G;

  for (int i = tid; i < 3 * G * 128; i += NT) {
    int e = i % 128, g = (i / 128) % G, t = i / (G * 128);
    X[(t * G + g) * 128 + e] = F2B(p.vecs[(size_t)(b0 + g) * 384 + t * 128 + e]);
  }
  if (tid < 128) clsb[tid] = p.in[I_PCLS][3 * 128 + tid];
  __syncthreads();
  compute_usb<128>(p.in[I_PWQKV] + (size_t)3 * 384 * 128, p.in[I_PBQKV] + 3 * 384,
                   clsb, attq, uLb, sbL);
  agg_run<128, 3>(X, clsb, uLb, sbL,
                  p.in[I_PWQKV] + (size_t)3 * 384 * 128 + 2 * 128 * 128,
                  p.in[I_PBQKV] + 3 * 384 + 256,
                  p.in[I_PWO] + (size_t)3 * 128 * 128, p.in[I_PBO] + 3 * 128,
                  p.in[I_PLNG] + 3 * 128, p.in[I_PLNB] + 3 * 128,
                  p.in[I_PW1] + (size_t)3 * 128 * 512, p.in[I_PB1] + 3 * 512,
                  p.in[I_PW2] + (size_t)3 * 512 * 128, p.in[I_PB2] + 3 * 128,
                  attq, xbar, ob, hb, mid);

  if (tid < G * 2) {
    int g = tid >> 1, c = tid & 1;
    const float* cw = p.in[I_CLFW];
    float acc = p.in[I_CLFB][c];
    for (int j = 0; j < 128; ++j) acc += ob[g * 128 + j] * cw[j * 2 + c];
    p.out[(size_t)(b0 + g) * 2 + c] = acc;
  }
}

extern "C" void kernel_launch(void* const* d_in, const int* in_sizes, int n_in,
                              void* d_out, int out_size, void* d_ws, size_t ws_size,
                              hipStream_t stream) {
  P p;
  for (int i = 0; i < 32; ++i) p.in[i] = (const float*)d_in[i];
  const int B = in_sizes[0] / (34 * 32);
  float* ws = (float*)d_ws;
  p.parent_al = ws;                        // B*256 floats
  p.vecs = ws + (size_t)B * 256;           // B*384 floats
  p.out = (float*)d_out;

  k_sub<<<dim3(B / G), dim3(NT), 0, stream>>>(p);
  k_parent<<<dim3(B / G, 3), dim3(NT), 0, stream>>>(p);
  k_pkt<<<dim3(B / G), dim3(NT), 0, stream>>>(p);
}

// Round 11
// 1336.180 us; speedup vs baseline: 1.3860x; 1.3860x over previous
//
#include <hip/hip_runtime.h>
#include <math.h>

#define NT 256
#define G 4

// fp32 problem. R11 = R10 (LDS diet: bf16 xbar/mid/uL, mid+ob aliased into dead
// X pool) with launch bounds reverted to (NT,4): R10's (NT,6/8) caused register
// spills (VGPR 40, 530MB scratch traffic). LDS 25.6KB still allows 6 blk/CU.

enum {
  I_LEAF = 0, I_SUB, I_SAW, I_SAB, I_LAW, I_LAB, I_PAW, I_PAB,
  I_SCLS, I_SWQKV, I_SBQKV, I_SWO, I_SBO, I_SLNG, I_SLNB, I_SW1, I_SB1, I_SW2, I_SB2,
  I_PCLS, I_PWQKV, I_PBQKV, I_PWO, I_PBO, I_PLNG, I_PLNB, I_PW1, I_PB1, I_PW2, I_PB2,
  I_CLFW, I_CLFB
};

struct P {
  const float* in[32];
  float* parent_al;  // ws [B][2][128]
  float* vecs;       // ws [B][3][128]
  float* out;        // [B][2]
};

using u16 = unsigned short;

__device__ __forceinline__ float uplo(unsigned int u) { return __uint_as_float(u << 16); }
__device__ __forceinline__ float uphi(unsigned int u) { return __uint_as_float(u & 0xffff0000u); }
__device__ __forceinline__ float B16F(u16 v) { return __uint_as_float((unsigned int)v << 16); }
__device__ __forceinline__ u16 F2B(float f) {  // RNE
  unsigned int u = __float_as_uint(f);
  return (u16)((u + 0x7FFFu + ((u >> 16) & 1u)) >> 16);
}
__device__ __forceinline__ void LD8(const float* p, float* o) {
  float4 a = ((const float4*)p)[0], b = ((const float4*)p)[1];
  o[0] = a.x; o[1] = a.y; o[2] = a.z; o[3] = a.w;
  o[4] = b.x; o[5] = b.y; o[6] = b.z; o[7] = b.w;
}
__device__ __forceinline__ void LDB8(const u16* p, float* o) {  // 8 bf16 -> fp32 (16B)
  uint4 u = *(const uint4*)p;
  o[0] = uplo(u.x); o[1] = uphi(u.x); o[2] = uplo(u.y); o[3] = uphi(u.y);
  o[4] = uplo(u.z); o[5] = uphi(u.z); o[6] = uplo(u.w); o[7] = uphi(u.w);
}
__device__ __forceinline__ void fma8(float& acc, const float* x, const float* w) {
#pragma unroll
  for (int i = 0; i < 8; ++i) acc += x[i] * w[i];
}
__device__ __forceinline__ float red8(float v) {  // reduce within 8 consecutive lanes
  v += __shfl_xor(v, 1, 64);
  v += __shfl_xor(v, 2, 64);
  v += __shfl_xor(v, 4, 64);
  return v;
}
__device__ __forceinline__ float gelu(float v) {
  return 0.5f * v * (1.0f + erff(v * 0.70710678118654752f));
}

// LayerNorm rows in place: buf [G][E]; one wave per row (G=4).
template <int E>
__device__ void ln_rows(float* buf, const float* __restrict__ gg, const float* __restrict__ bb) {
  const int w = threadIdx.x >> 6, lane = threadIdx.x & 63;
  for (int g = w; g < G; g += 4) {
    float* row = buf + g * E;
    float s = 0.f, s2 = 0.f;
    for (int e = lane; e < E; e += 64) { float x = row[e]; s += x; s2 += x * x; }
#pragma unroll
    for (int off = 1; off < 64; off <<= 1) {
      s += __shfl_xor(s, off, 64);
      s2 += __shfl_xor(s2, off, 64);
    }
    float m = s / (float)E;
    float inv = 1.0f / sqrtf(s2 / (float)E - m * m + 1e-5f);
    for (int e = lane; e < E; e += 64) row[e] = (row[e] - m) * inv * gg[e] + bb[e];
  }
}

// q = Wq.cls + bq (coalesced k-split) ; uLb (bf16) = scale*Wk_h^T q_h ; sb_h
template <int E>
__device__ void compute_usb(const float* __restrict__ Wq, const float* __restrict__ bq,
                            const float* __restrict__ clsb, float* qb,
                            u16* uLb, float* sbL) {
  const int tid = threadIdx.x;
  constexpr int D = E / 4;
  const float scale = (D == 16) ? 0.25f : 0.17677669529663687f;
  const int ks = tid & 7, eb = tid >> 3;
  for (int e = eb; e < E; e += NT / 8) {
    const float* w = Wq + (size_t)e * E + ks * 8;
    float acc = 0.f;
    for (int kc = 0; kc < E; kc += 64) {
      float wv[8], xv[8];
      LD8(w + kc, wv);
      LD8(clsb + kc + ks * 8, xv);
      fma8(acc, xv, wv);
    }
    acc = red8(acc);
    if (ks == 0) qb[e] = bq[e] + acc;
  }
  __syncthreads();
  if (tid < E) {
    for (int h = 0; h < 4; ++h) {
      float acc = 0.f;
      for (int d = 0; d < D; ++d)
        acc += Wq[(size_t)(E + h * D + d) * E + tid] * qb[h * D + d];
      uLb[h * E + tid] = F2B(acc * scale);
    }
  }
  if (tid < 4) {
    float acc = 0.f;
    for (int d = 0; d < D; ++d) acc += qb[tid * D + d] * bq[E + tid * D + d];
    sbL[tid] = acc * scale;
  }
  __syncthreads();
}

// Folded CLS-only aggregator over G batches. X: LDS bf16, row (t*G+g), E elems.
// mid (bf16) and ob (fp32) alias the X pool (X dead after xbar phase).
// Result fp32 [G][E] in ob. Ends with barrier.
template <int E, int T>
__device__ void agg_run(const u16* __restrict__ X, const float* __restrict__ clsb,
                        const u16* __restrict__ uLb, const float* __restrict__ sbL,
                        const float* __restrict__ Wv, const float* __restrict__ bv,
                        const float* __restrict__ Wo, const float* __restrict__ bo,
                        const float* __restrict__ lng, const float* __restrict__ lnb,
                        const float* __restrict__ W1, const float* __restrict__ b1,
                        const float* __restrict__ W2, const float* __restrict__ b2,
                        float* att, u16* xbar, float* ob, float* hb, u16* mid) {
  const int tid = threadIdx.x;
  const int wid = tid >> 6, lane = tid & 63;
  const int ks = tid & 7, eb = tid >> 3;
  constexpr int S = T + 1, D = E / 4;
  constexpr int GPT = (G * E) / NT;          // outputs/thread in FFN2
  constexpr int M1 = (4 * E) / NT;           // FFN1 outputs/thread

  // ---- scores[g][h][s] = sb[h] + x_s . u_h : one dot per wave-iteration ----
  for (int i = wid; i < G * 4 * S; i += 4) {
    int s = i % S, hh = (i / S) % 4, g = i / (4 * S);
    float part = 0.f;
    if (lane < E / 2) {
      unsigned int uv = ((const unsigned int*)(uLb + hh * E))[lane];
      if (s == 0) {
        float2 c2 = ((const float2*)clsb)[lane];
        part = c2.x * uplo(uv) + c2.y * uphi(uv);
      } else {
        unsigned int xv = ((const unsigned int*)(X + ((s - 1) * G + g) * E))[lane];
        part = uplo(xv) * uplo(uv) + uphi(xv) * uphi(uv);
      }
    }
#pragma unroll
    for (int off = 1; off < 64; off <<= 1) part += __shfl_xor(part, off, 64);
    if (lane == 0) att[(g * 4 + hh) * S + s] = sbL[hh] + part;
  }
  __syncthreads();
  // ---- softmax over s ----
  for (int i = tid; i < G * 4; i += NT) {
    float* a = att + i * S;
    float mx = a[0];
    for (int s = 1; s < S; ++s) mx = fmaxf(mx, a[s]);
    float sum = 0.f;
    for (int s = 0; s < S; ++s) { float e = expf(a[s] - mx); a[s] = e; sum += e; }
    float inv = 1.0f / sum;
    for (int s = 0; s < S; ++s) a[s] *= inv;
  }
  __syncthreads();
  // ---- xbar[g][h][k] = a0*cls[k] + sum_s att*x_s[k]  (2 k's per thread, packed) ----
  for (int i = tid; i < G * 4 * (E / 2); i += NT) {
    int k2 = i % (E / 2), hh = (i / (E / 2)) % 4, g = i / (4 * (E / 2));
    const float* a = att + (g * 4 + hh) * S;
    float acc0 = a[0] * clsb[2 * k2], acc1 = a[0] * clsb[2 * k2 + 1];
    for (int s = 1; s < S; ++s) {
      unsigned int xv = ((const unsigned int*)(X + ((s - 1) * G + g) * E))[k2];
      acc0 += a[s] * uplo(xv);
      acc1 += a[s] * uphi(xv);
    }
    ((unsigned int*)xbar)[(g * 4 + hh) * (E / 2) + k2] =
        (unsigned int)F2B(acc0) | ((unsigned int)F2B(acc1) << 16);
  }
  __syncthreads();
  // ---- ob[g][e] = bv[e] + Wv[e][:] . xbar[g][head(e)][:]  (k-split, coalesced) ----
  for (int e = eb; e < E; e += NT / 8) {
    const int hh = e / D;
    const float* w = Wv + (size_t)e * E + ks * 8;
    float acc[G];
#pragma unroll
    for (int g = 0; g < G; ++g) acc[g] = 0.f;
    for (int kc = 0; kc < E; kc += 64) {
      float wv[8];
      LD8(w + kc, wv);
#pragma unroll
      for (int g = 0; g < G; ++g) {
        float xv[8];
        LDB8(xbar + (g * 4 + hh) * E + kc + ks * 8, xv);
        fma8(acc[g], xv, wv);
      }
    }
#pragma unroll
    for (int g = 0; g < G; ++g) {
      float v = red8(acc[g]);
      if (ks == 0) ob[g * E + e] = bv[e] + v;
    }
  }
  __syncthreads();
  // ---- hb[g][e] = bo[e] + cls[e] + Wo[e][:] . ob[g][:]  (k-split, coalesced) ----
  for (int e = eb; e < E; e += NT / 8) {
    const float* w = Wo + (size_t)e * E + ks * 8;
    float acc[G];
#pragma unroll
    for (int g = 0; g < G; ++g) acc[g] = 0.f;
    for (int kc = 0; kc < E; kc += 64) {
      float wv[8];
      LD8(w + kc, wv);
#pragma unroll
      for (int g = 0; g < G; ++g) {
        float xv[8];
        LD8(ob + g * E + kc + ks * 8, xv);
        fma8(acc[g], xv, wv);
      }
    }
#pragma unroll
    for (int g = 0; g < G; ++g) {
      float v = red8(acc[g]);
      if (ks == 0) hb[g * E + e] = bo[e] + clsb[e] + v;
    }
  }
  __syncthreads();
  ln_rows<E>(hb, lng, lnb);
  __syncthreads();
  // ---- FFN1: mid[g][m] = gelu(hb[g] @ W1 + b1)  (bf16 store, packed) ----
  {
    float acc[M1][G];
#pragma unroll
    for (int r = 0; r < M1; ++r)
#pragma unroll
      for (int g = 0; g < G; ++g) acc[r][g] = 0.f;
    for (int j = 0; j < E; j += 8) {
      float wv[M1][8];
#pragma unroll
      for (int ii = 0; ii < 8; ++ii) {
        if constexpr (M1 == 2) {
          float2 w2 = *(const float2*)(W1 + (size_t)(j + ii) * 4 * E + 2 * tid);
          wv[0][ii] = w2.x;
          wv[1][ii] = w2.y;
        } else {
          wv[0][ii] = W1[(size_t)(j + ii) * 4 * E + tid];
        }
      }
#pragma unroll
      for (int g = 0; g < G; ++g) {
        float xv[8];
        LD8(hb + g * E + j, xv);
#pragma unroll
        for (int r = 0; r < M1; ++r) fma8(acc[r][g], xv, wv[r]);
      }
    }
    if constexpr (M1 == 2) {
#pragma unroll
      for (int g = 0; g < G; ++g) {
        float v0 = gelu(acc[0][g] + b1[2 * tid]);
        float v1 = gelu(acc[1][g] + b1[2 * tid + 1]);
        ((unsigned int*)mid)[g * (2 * E) + tid] =
            (unsigned int)F2B(v0) | ((unsigned int)F2B(v1) << 16);
      }
    } else {
#pragma unroll
      for (int g = 0; g < G; ++g)
        mid[g * 4 * E + tid] = F2B(gelu(acc[0][g] + b1[tid]));
    }
  }
  __syncthreads();
  // ---- FFN2 + residual -> ob; LN2 ----
  {
    const int e = tid % E, gp = tid / E;
    float acc[GPT];
#pragma unroll
    for (int r = 0; r < GPT; ++r) acc[r] = 0.f;
    for (int m = 0; m < 4 * E; m += 8) {
      float wv[8];
#pragma unroll
      for (int ii = 0; ii < 8; ++ii) wv[ii] = W2[(size_t)(m + ii) * E + e];
#pragma unroll
      for (int r = 0; r < GPT; ++r) {
        float xv[8];
        LDB8(mid + (gp * GPT + r) * 4 * E + m, xv);
        fma8(acc[r], xv, wv);
      }
    }
#pragma unroll
    for (int r = 0; r < GPT; ++r) {
      int g = gp * GPT + r;
      ob[g * E + e] = b2[e] + hb[g * E + e] + acc[r];
    }
  }
  __syncthreads();
  ln_rows<E>(ob, lng, lnb);
  __syncthreads();
}

// ===================== kernel 1: sub path =====================
__global__ __launch_bounds__(NT, 4) void k_sub(P p) {
  __shared__ __align__(16) u16 pool[8 * G * 64];   // X1; later mid(1024 u16)+ob(256 f)
  __shared__ __align__(16) u16 X2[3 * G * 64];
  __shared__ __align__(16) float clsb[64];
  __shared__ __align__(16) u16 uLb[4 * 64];
  __shared__ __align__(16) float sbL[4];
  __shared__ __align__(16) float attq[G * 4 * 9];   // also usb qb scratch (>=64 f)
  __shared__ __align__(16) u16 xbar[G * 4 * 64];
  __shared__ __align__(16) float hb[G * 64];
  __shared__ __align__(16) float vec1[G * 64];
  u16* X1 = pool;
  u16* mid = pool;                                  // [0, 1024) u16
  float* ob = (float*)(pool + 1024);                // [2048, 3072) bytes
  const int tid = threadIdx.x, b0 = blockIdx.x * G;

  // subfield align: X[f][g][e]
  const float* subf = p.in[I_SUB];
  const float* saW = p.in[I_SAW];
  const float* sab = p.in[I_SAB];
  for (int i = tid; i < 11 * 64; i += NT) {
    int f = i / 64, e = i % 64;
    float bias = sab[f * 64 + e];
    float acc[G];
#pragma unroll
    for (int g = 0; g < G; ++g) acc[g] = bias;
    for (int d = 0; d < 32; d += 8) {
      float wv[8];
#pragma unroll
      for (int ii = 0; ii < 8; ++ii) wv[ii] = saW[(size_t)(f * 32 + d + ii) * 64 + e];
#pragma unroll
      for (int g = 0; g < G; ++g) {
        float xv[8];
        LD8(subf + (size_t)(b0 + g) * 352 + f * 32 + d, xv);
        fma8(acc[g], xv, wv);
      }
    }
#pragma unroll
    for (int g = 0; g < G; ++g) {
      if (f < 8) X1[(f * G + g) * 64 + e] = F2B(acc[g]);
      else       X2[((f - 8) * G + g) * 64 + e] = F2B(acc[g]);
    }
  }
  if (tid < 64) clsb[tid] = p.in[I_SCLS][tid];
  __syncthreads();

  // agg1: tcp.flags (subfields 0..7)
  compute_usb<64>(p.in[I_SWQKV], p.in[I_SBQKV], clsb, attq, uLb, sbL);
  agg_run<64, 8>(X1, clsb, uLb, sbL,
                 p.in[I_SWQKV] + 2 * 64 * 64, p.in[I_SBQKV] + 128,
                 p.in[I_SWO], p.in[I_SBO], p.in[I_SLNG], p.in[I_SLNB],
                 p.in[I_SW1], p.in[I_SB1], p.in[I_SW2], p.in[I_SB2],
                 attq, xbar, ob, hb, mid);
  for (int i = tid; i < G * 64; i += NT) vec1[i] = ob[i];
  if (tid < 64) clsb[tid] = p.in[I_SCLS][64 + tid];
  __syncthreads();

  // agg2: ip.flags (subfields 8..10)
  compute_usb<64>(p.in[I_SWQKV] + 192 * 64, p.in[I_SBQKV] + 192, clsb, attq, uLb, sbL);
  agg_run<64, 3>(X2, clsb, uLb, sbL,
                 p.in[I_SWQKV] + 192 * 64 + 2 * 64 * 64, p.in[I_SBQKV] + 192 + 128,
                 p.in[I_SWO] + 64 * 64, p.in[I_SBO] + 64,
                 p.in[I_SLNG] + 64, p.in[I_SLNB] + 64,
                 p.in[I_SW1] + 64 * 256, p.in[I_SB1] + 256,
                 p.in[I_SW2] + 256 * 64, p.in[I_SB2] + 64,
                 attq, xbar, ob, hb, mid);

  // parent_al: [:,0] = tcpf @ paW0 + pab0 ; [:,1] = ipf @ paW1 + pab1
  {
    const int pi = tid >> 7, e = tid & 127;
    const float* paW = p.in[I_PAW];
    float bias = p.in[I_PAB][pi * 128 + e];
    float acc[G];
#pragma unroll
    for (int g = 0; g < G; ++g) acc[g] = bias;
    const float* src = pi ? ob : vec1;
    for (int j = 0; j < 64; j += 8) {
      float wv[8];
#pragma unroll
      for (int ii = 0; ii < 8; ++ii) wv[ii] = paW[(size_t)(pi * 64 + j + ii) * 128 + e];
#pragma unroll
      for (int g = 0; g < G; ++g) {
        float xv[8];
        LD8(src + g * 64 + j, xv);
        fma8(acc[g], xv, wv);
      }
    }
#pragma unroll
    for (int g = 0; g < G; ++g)
      p.parent_al[(size_t)(b0 + g) * 256 + pi * 128 + e] = acc[g];
  }
}

// ===================== kernel 2: parent aggs =====================
template <int T, int F, int F0, int PAR, int AI>
__device__ void parent_body(const P& p, int b0, u16* pool, float* clsb,
                            u16* uLb, float* sbL, float* attq, u16* xbar,
                            float* hb) {
  const int tid = threadIdx.x;
  u16* X = pool;
  u16* mid = pool;                                  // [0, 2048) u16
  float* ob = (float*)(pool + 2048);                // [4096, 6144) bytes
  const float* leaf = p.in[I_LEAF];
  const float* laW = p.in[I_LAW];
  const float* lab = p.in[I_LAB];
  for (int i = tid; i < F * 128; i += NT) {
    int f = i / 128, e = i % 128;
    float bias = lab[(F0 + f) * 128 + e];
    float acc[G];
#pragma unroll
    for (int g = 0; g < G; ++g) acc[g] = bias;
    for (int d = 0; d < 32; d += 8) {
      float wv[8];
#pragma unroll
      for (int ii = 0; ii < 8; ++ii)
        wv[ii] = laW[(size_t)((F0 + f) * 32 + d + ii) * 128 + e];
#pragma unroll
      for (int g = 0; g < G; ++g) {
        float xv[8];
        LD8(leaf + (size_t)(b0 + g) * 1088 + (F0 + f) * 32 + d, xv);
        fma8(acc[g], xv, wv);
      }
    }
#pragma unroll
    for (int g = 0; g < G; ++g) X[(f * G + g) * 128 + e] = F2B(acc[g]);
  }
  if (PAR >= 0) {
    for (int i = tid; i < G * 128; i += NT) {
      int g = i / 128, e = i % 128;
      X[((T - 1) * G + g) * 128 + e] =
          F2B(p.parent_al[(size_t)(b0 + g) * 256 + PAR * 128 + e]);
    }
  }
  if (tid < 128) clsb[tid] = p.in[I_PCLS][AI * 128 + tid];
  __syncthreads();
  compute_usb<128>(p.in[I_PWQKV] + (size_t)AI * 384 * 128, p.in[I_PBQKV] + AI * 384,
                   clsb, attq, uLb, sbL);
  agg_run<128, T>(X, clsb, uLb, sbL,
                  p.in[I_PWQKV] + (size_t)AI * 384 * 128 + 2 * 128 * 128,
                  p.in[I_PBQKV] + AI * 384 + 256,
                  p.in[I_PWO] + (size_t)AI * 128 * 128, p.in[I_PBO] + AI * 128,
                  p.in[I_PLNG] + AI * 128, p.in[I_PLNB] + AI * 128,
                  p.in[I_PW1] + (size_t)AI * 128 * 512, p.in[I_PB1] + AI * 512,
                  p.in[I_PW2] + (size_t)AI * 512 * 128, p.in[I_PB2] + AI * 128,
                  attq, xbar, ob, hb, mid);
  for (int i = tid; i < G * 128; i += NT) {
    int e = i % 128, g = i / 128;
    p.vecs[(size_t)(b0 + g) * 384 + AI * 128 + e] = ob[g * 128 + e];
  }
}

__global__ __launch_bounds__(NT, 4) void k_parent(P p) {
  __shared__ __align__(16) u16 pool[16 * G * 128];  // X; later mid+ob
  __shared__ __align__(16) float clsb[128];
  __shared__ __align__(16) u16 uLb[4 * 128];
  __shared__ __align__(16) float sbL[4];
  __shared__ __align__(16) float attq[G * 4 * 17];  // also usb qb scratch (>=128 f)
  __shared__ __align__(16) u16 xbar[G * 4 * 128];
  __shared__ __align__(16) float hb[G * 128];
  const int b0 = blockIdx.x * G;
  if (blockIdx.y == 0)
    parent_body<8, 8, 0, -1, 0>(p, b0, pool, clsb, uLb, sbL, attq, xbar, hb);
  else if (blockIdx.y == 1)
    parent_body<12, 11, 8, 1, 1>(p, b0, pool, clsb, uLb, sbL, attq, xbar, hb);
  else
    parent_body<16, 15, 19, 0, 2>(p, b0, pool, clsb, uLb, sbL, attq, xbar, hb);
}

// ===================== kernel 3: pkt agg + classifier =====================
__global__ __launch_bounds__(NT, 4) void k_pkt(P p) {
  __shared__ __align__(16) u16 pool[3072];          // X (1536 u16); mid(2048)+ob
  __shared__ __align__(16) float clsb[128];
  __shared__ __align__(16) u16 uLb[4 * 128];
  __shared__ __align__(16) float sbL[4];
  __shared__ __align__(16) float attq[128];         // max(G*4*S=64, qb E=128)
  __shared__ __align__(16) u16 xbar[G * 4 * 128];
  __shared__ __align__(16) float hb[G * 128];
  u16* X = pool;
  u16* mid = pool;                                  // [0, 2048) u16
  float* ob = (float*)(pool + 2048);                // [4096, 6144) bytes
  const int tid = threadIdx.x, b0 = blockIdx.x * G;

  for (int i = tid; i < 3 * G * 128; i += NT) {
    int e = i % 128, g = (i / 128) % G, t = i / (G * 128);
    X[(t * G + g) * 128 + e] = F2B(p.vecs[(size_t)(b0 + g) * 384 + t * 128 + e]);
  }
  if (tid < 128) clsb[tid] = p.in[I_PCLS][3 * 128 + tid];
  __syncthreads();
  compute_usb<128>(p.in[I_PWQKV] + (size_t)3 * 384 * 128, p.in[I_PBQKV] + 3 * 384,
                   clsb, attq, uLb, sbL);
  agg_run<128, 3>(X, clsb, uLb, sbL,
                  p.in[I_PWQKV] + (size_t)3 * 384 * 128 + 2 * 128 * 128,
                  p.in[I_PBQKV] + 3 * 384 + 256,
                  p.in[I_PWO] + (size_t)3 * 128 * 128, p.in[I_PBO] + 3 * 128,
                  p.in[I_PLNG] + 3 * 128, p.in[I_PLNB] + 3 * 128,
                  p.in[I_PW1] + (size_t)3 * 128 * 512, p.in[I_PB1] + 3 * 512,
                  p.in[I_PW2] + (size_t)3 * 512 * 128, p.in[I_PB2] + 3 * 128,
                  attq, xbar, ob, hb, mid);

  if (tid < G * 2) {
    int g = tid >> 1, c = tid & 1;
    const float* cw = p.in[I_CLFW];
    float acc = p.in[I_CLFB][c];
    for (int j = 0; j < 128; ++j) acc += ob[g * 128 + j] * cw[j * 2 + c];
    p.out[(size_t)(b0 + g) * 2 + c] = acc;
  }
}

extern "C" void kernel_launch(void* const* d_in, const int* in_sizes, int n_in,
                              void* d_out, int out_size, void* d_ws, size_t ws_size,
                              hipStream_t stream) {
  P p;
  for (int i = 0; i < 32; ++i) p.in[i] = (const float*)d_in[i];
  const int B = in_sizes[0] / (34 * 32);
  float* ws = (float*)d_ws;
  p.parent_al = ws;                        // B*256 floats
  p.vecs = ws + (size_t)B * 256;           // B*384 floats
  p.out = (float*)d_out;

  k_sub<<<dim3(B / G), dim3(NT), 0, stream>>>(p);
  k_parent<<<dim3(B / G, 3), dim3(NT), 0, stream>>>(p);
  k_pkt<<<dim3(B / G), dim3(NT), 0, stream>>>(p);
}